// Round 12
// baseline (491.381 us; speedup 1.0000x reference)
//
#include <hip/hip_runtime.h>
#include <math.h>

#define NUM_NODES 94
#define SEQ_LEN 784
#define OUT_CLASSES 10

#define TWO_GAMMA 0.2f
#define OM2 0.0503551324598949f            // (2*pi/28)^2
#define INV_SQRT_N 0.103142124625879       // 1/sqrt(94)
#define LOG2E 1.4426950408889634
// exp2 arg = 2A*log2e -> fold 2*INV_SQRT_N*LOG2E into all I-path weights
#define WSCALE ((float)(2.0 * INV_SQRT_N * LOG2E))

typedef _Float16 h2 __attribute__((ext_vector_type(2)));
typedef _Float16 h4 __attribute__((ext_vector_type(4)));

__device__ __forceinline__ float dpp_xor1(float x) {   // quad_perm(1,0,3,2)
    return __int_as_float(__builtin_amdgcn_mov_dpp(__float_as_int(x), 0xB1, 0xF, 0xF, true));
}
__device__ __forceinline__ float dpp_xor2(float x) {   // quad_perm(2,3,0,1)
    return __int_as_float(__builtin_amdgcn_mov_dpp(__float_as_int(x), 0x4E, 0xF, 0xF, true));
}
__device__ __forceinline__ float dpp_mir8(float x) {   // ROW_HALF_MIRROR: i<->i^7
    return __int_as_float(__builtin_amdgcn_mov_dpp(__float_as_int(x), 0x141, 0xF, 0xF, true));
}

__device__ __forceinline__ float dot2(h2 a, h2 b, float c) {
#if __has_builtin(__builtin_amdgcn_fdot2)
    return __builtin_amdgcn_fdot2(a, b, c, false);   // v_dot2_f32_f16
#else
    return c + (float)a[0] * (float)b[0] + (float)a[1] * (float)b[1];
#endif
}

// R11 (315us, VALUBusy 60%) was latency-bound: 842 cyc/step vs ~220 issue —
// the LDS round-trip + dpp/dynamics chains are exposed at 1 wave/SIMD.
// R12: TWO independent elements per wave. Their chains interleave, so one
// element's issue hides the other's latency. W block + node mapping + biases
// are shared (same lane->row assignment for both elements): only ~+30 regs.
__global__
__attribute__((amdgpu_flat_work_group_size(64, 64), amdgpu_waves_per_eu(1, 1)))
void horn_kernel(
    const float* __restrict__ input,   // (1024, 784)
    const float* __restrict__ w_ih,    // (94, 1)
    const float* __restrict__ b_ih,    // (94)
    const float* __restrict__ w_hh,    // (94, 94)
    const float* __restrict__ b_hh,    // (94)
    const float* __restrict__ w_ro,    // (10, 94)
    const float* __restrict__ b_ro,    // (10)
    float* __restrict__ out)           // (1024, 10)
{
    __shared__ __align__(16) _Float16 ysh[2][96];   // per-element y (f16)
    __shared__ __align__(16) float    xsh[2][96];   // epilogue x gather

    const int lane = threadIdx.x;      // 0..63
    const int g    = lane >> 3;        // row-group: rows 12g..12g+11
    const int lw   = lane & 7;         // col-chunk: cols 12lw..12lw+11
    const int e0   = blockIdx.x * 2;   // two batch elements per wave

    const int b0  = lane & 1, b1 = (lane >> 1) & 1, b2v = (lane >> 2) & 1;
    const int c0i = b0 ^ b2v;
    const int c1i = b1 ^ b2v;
    const int c2i = b2v;

    const int row0 = 12 * g, col0 = 12 * lw;

    // ---- W block with folded row permutation (select-free butterfly),
    //      f16-packed, pre-scaled. Shared by both elements. ----
    h2 w2[12][6];
    #pragma unroll
    for (int j = 0; j < 12; j++) {
        int rr;
        if (j < 8) {
            rr = row0 + 4 * (((j >> 2) & 1) ^ c2i)
                      + 2 * (((j >> 1) & 1) ^ c1i)
                      +     ((j & 1) ^ c0i);
        } else {
            const int jj = j - 8;
            rr = row0 + 8 + 2 * (((jj >> 1) & 1) ^ c1i)
                          +     ((jj & 1) ^ c0i);
        }
        #pragma unroll
        for (int c = 0; c < 12; c++) {
            const int cc = col0 + c;
            float v = (rr < NUM_NODES && cc < NUM_NODES)
                        ? w_hh[rr * NUM_NODES + cc] * WSCALE : 0.0f;
            w2[j][c >> 1][c & 1] = (_Float16)v;
        }
    }

    // Owned rows (verified machinery R6-R11) — same for both elements.
    const int nA = row0 + 4 * c2i + 2 * c1i + c0i;
    const int nB = row0 + 8 + 2 * c1i + c0i;
    const float wihA  = (nA < NUM_NODES) ? w_ih[nA] * WSCALE : 0.0f;
    const float biasA = (nA < NUM_NODES) ? (b_ih[nA] + b_hh[nA]) * WSCALE : 0.0f;
    const float wihB  = (nB < NUM_NODES) ? w_ih[nB] * WSCALE : 0.0f;
    const float biasB = (nB < NUM_NODES) ? (b_ih[nB] + b_hh[nB]) * WSCALE : 0.0f;

    float xA0 = 0.f, yA0 = 0.f, xB0 = 0.f, yB0 = 0.f;   // element 0 state
    float xA1 = 0.f, yA1 = 0.f, xB1 = 0.f, yB1 = 0.f;   // element 1 state

    ysh[0][nA] = (_Float16)0.f;  ysh[0][nB] = (_Float16)0.f;
    ysh[1][nA] = (_Float16)0.f;  ysh[1][nB] = (_Float16)0.f;
    asm volatile("s_waitcnt lgkmcnt(0)" ::: "memory");

    const float* srow0 = input + (size_t)e0 * SEQ_LEN;
    const float* srow1 = srow0 + SEQ_LEN;
    float sc0 = srow0[0];
    float sc1 = srow1[0];

    const h4* yv0 = (const h4*)&ysh[0][col0];   // byte 24*lw: 8B-aligned
    const h4* yv1 = (const h4*)&ysh[1][col0];

    for (int t = 0; t < SEQ_LEN; t++) {
        const int tn = (t + 1 < SEQ_LEN) ? t + 1 : (SEQ_LEN - 1);
        float sn0 = srow0[tn];
        float sn1 = srow1[tn];

        // ---- read both elements' 12-col y chunks (6x ds_read_b64) ----
        h4 Y00 = yv0[0], Y01 = yv0[1], Y02 = yv0[2];
        h4 Y10 = yv1[0], Y11 = yv1[1], Y12 = yv1[2];
        h2 a0 = __builtin_shufflevector(Y00, Y00, 0, 1);
        h2 a1 = __builtin_shufflevector(Y00, Y00, 2, 3);
        h2 a2 = __builtin_shufflevector(Y01, Y01, 0, 1);
        h2 a3 = __builtin_shufflevector(Y01, Y01, 2, 3);
        h2 a4 = __builtin_shufflevector(Y02, Y02, 0, 1);
        h2 a5 = __builtin_shufflevector(Y02, Y02, 2, 3);
        h2 b0v = __builtin_shufflevector(Y10, Y10, 0, 1);
        h2 b1v = __builtin_shufflevector(Y10, Y10, 2, 3);
        h2 b2w = __builtin_shufflevector(Y11, Y11, 0, 1);
        h2 b3v = __builtin_shufflevector(Y11, Y11, 2, 3);
        h2 b4v = __builtin_shufflevector(Y12, Y12, 0, 1);
        h2 b5v = __builtin_shufflevector(Y12, Y12, 2, 3);

        // ---- dots for both elements, interleaved (independent chains) ----
        float P0[12], P1[12];
        #pragma unroll
        for (int i = 0; i < 12; i++) {
            float p = dot2(w2[i][0], a0, 0.0f);
            float q = dot2(w2[i][0], b0v, 0.0f);
            p = dot2(w2[i][1], a1, p);   q = dot2(w2[i][1], b1v, q);
            p = dot2(w2[i][2], a2, p);   q = dot2(w2[i][2], b2w, q);
            p = dot2(w2[i][3], a3, p);   q = dot2(w2[i][3], b3v, q);
            p = dot2(w2[i][4], a4, p);   q = dot2(w2[i][4], b4v, q);
            p = dot2(w2[i][5], a5, p);   q = dot2(w2[i][5], b5v, q);
            P0[i] = p;  P1[i] = q;
        }

        // ---- select-free butterflies, interleaved ----
        float Q00 = P0[0]  + dpp_xor1(P0[1]);
        float Q10 = P1[0]  + dpp_xor1(P1[1]);
        float Q01 = P0[2]  + dpp_xor1(P0[3]);
        float Q11 = P1[2]  + dpp_xor1(P1[3]);
        float Q02 = P0[4]  + dpp_xor1(P0[5]);
        float Q12 = P1[4]  + dpp_xor1(P1[5]);
        float Q03 = P0[6]  + dpp_xor1(P0[7]);
        float Q13 = P1[6]  + dpp_xor1(P1[7]);
        float Q04 = P0[8]  + dpp_xor1(P0[9]);
        float Q14 = P1[8]  + dpp_xor1(P1[9]);
        float Q05 = P0[10] + dpp_xor1(P0[11]);
        float Q15 = P1[10] + dpp_xor1(P1[11]);
        float R00 = Q00 + dpp_xor2(Q01);
        float R10 = Q10 + dpp_xor2(Q11);
        float R01 = Q02 + dpp_xor2(Q03);
        float R11 = Q12 + dpp_xor2(Q13);
        float R02 = Q04 + dpp_xor2(Q05);
        float R12 = Q14 + dpp_xor2(Q15);
        float SA0 = R00 + dpp_mir8(R01);
        float SA1 = R10 + dpp_mir8(R11);
        float SB0 = R02 + dpp_mir8(R02);
        float SB1 = R12 + dpp_mir8(R12);

        // ---- dynamics, interleaved ----
        float eA0 = __builtin_amdgcn_exp2f(fmaf(sc0, wihA, biasA) + SA0);
        float eA1 = __builtin_amdgcn_exp2f(fmaf(sc1, wihA, biasA) + SA1);
        float eB0 = __builtin_amdgcn_exp2f(fmaf(sc0, wihB, biasB) + SB0);
        float eB1 = __builtin_amdgcn_exp2f(fmaf(sc1, wihB, biasB) + SB1);
        float aA0 = 0.5f - __builtin_amdgcn_rcpf(eA0 + 1.0f);
        float aA1 = 0.5f - __builtin_amdgcn_rcpf(eA1 + 1.0f);
        float aB0 = 0.5f - __builtin_amdgcn_rcpf(eB0 + 1.0f);
        float aB1 = 0.5f - __builtin_amdgcn_rcpf(eB1 + 1.0f);
        aA0 = fmaf(-TWO_GAMMA, yA0, aA0);  aA0 = fmaf(-OM2, xA0, aA0);
        aA1 = fmaf(-TWO_GAMMA, yA1, aA1);  aA1 = fmaf(-OM2, xA1, aA1);
        aB0 = fmaf(-TWO_GAMMA, yB0, aB0);  aB0 = fmaf(-OM2, xB0, aB0);
        aB1 = fmaf(-TWO_GAMMA, yB1, aB1);  aB1 = fmaf(-OM2, xB1, aB1);
        xA0 += yA0;  yA0 += aA0;
        xA1 += yA1;  yA1 += aA1;
        xB0 += yB0;  yB0 += aB0;
        xB1 += yB1;  yB1 += aB1;

        // ---- publish new y (wave-lockstep + fence; no barrier) ----
        ysh[0][nA] = (_Float16)yA0;
        ysh[1][nA] = (_Float16)yA1;
        ysh[0][nB] = (_Float16)yB0;
        ysh[1][nB] = (_Float16)yB1;
        asm volatile("s_waitcnt lgkmcnt(0)" ::: "memory");

        sc0 = sn0;
        sc1 = sn1;
    }

    // ---- epilogue: gather x, project both elements ----
    xsh[0][nA] = xA0;  xsh[0][nB] = xB0;
    xsh[1][nA] = xA1;  xsh[1][nB] = xB1;
    asm volatile("s_waitcnt lgkmcnt(0)" ::: "memory");

    {
        const int e = lane >> 4;           // 0,1 for lanes 0-15 / 16-31
        const int c = lane & 15;
        if (e < 2 && c < OUT_CLASSES) {
            float acc = b_ro[c];
            #pragma unroll 2
            for (int j = 0; j < NUM_NODES; j++) {
                acc += xsh[e][j] * w_ro[c * NUM_NODES + j];
            }
            out[(size_t)(e0 + e) * OUT_CLASSES + c] = acc;
        }
    }
}

extern "C" void kernel_launch(void* const* d_in, const int* in_sizes, int n_in,
                              void* d_out, int out_size, void* d_ws, size_t ws_size,
                              hipStream_t stream) {
    const float* input = (const float*)d_in[0];
    const float* w_ih  = (const float*)d_in[1];
    const float* b_ih  = (const float*)d_in[2];
    const float* w_hh  = (const float*)d_in[3];
    const float* b_hh  = (const float*)d_in[4];
    const float* w_ro  = (const float*)d_in[5];
    const float* b_ro  = (const float*)d_in[6];
    float* out = (float*)d_out;

    const int batch = in_sizes[0] / SEQ_LEN;   // 1024
    dim3 grid(batch / 2);                      // 512 blocks, 2 elements each
    dim3 block(64);

    hipLaunchKernelGGL(horn_kernel, grid, block, 0, stream,
                       input, w_ih, b_ih, w_hh, b_hh, w_ro, b_ro, out);
}

// Round 13
// 308.638 us; speedup vs baseline: 1.5921x; 1.5921x over previous
//
#include <hip/hip_runtime.h>
#include <math.h>

#define NUM_NODES 94
#define SEQ_LEN 784
#define OUT_CLASSES 10

#define TWO_GAMMA 0.2f
#define OM2 0.0503551324598949f            // (2*pi/28)^2
#define INV_SQRT_N 0.103142124625879       // 1/sqrt(94)
#define LOG2E 1.4426950408889634
// exp2 arg = 2A*log2e -> fold 2*INV_SQRT_N*LOG2E into all I-path weights
#define WSCALE ((float)(2.0 * INV_SQRT_N * LOG2E))

typedef _Float16 h2 __attribute__((ext_vector_type(2)));
typedef _Float16 h4 __attribute__((ext_vector_type(4)));
typedef float f4 __attribute__((ext_vector_type(4)));

__device__ __forceinline__ float dpp_xor1(float x) {   // quad_perm(1,0,3,2)
    return __int_as_float(__builtin_amdgcn_mov_dpp(__float_as_int(x), 0xB1, 0xF, 0xF, true));
}
__device__ __forceinline__ float dpp_xor2(float x) {   // quad_perm(2,3,0,1)
    return __int_as_float(__builtin_amdgcn_mov_dpp(__float_as_int(x), 0x4E, 0xF, 0xF, true));
}
__device__ __forceinline__ float dpp_mir8(float x) {   // ROW_HALF_MIRROR: i<->i^7
    return __int_as_float(__builtin_amdgcn_mov_dpp(__float_as_int(x), 0x141, 0xF, 0xF, true));
}

__device__ __forceinline__ float dot2(h2 a, h2 b, float c) {
#if __has_builtin(__builtin_amdgcn_fdot2)
    return __builtin_amdgcn_fdot2(a, b, c, false);   // v_dot2_f32_f16
#else
    return c + (float)a[0] * (float)b[0] + (float)a[1] * (float)b[1];
#endif
}

// R11 skeleton (best=315us, verified absmax 1.95e-3) minus two self-inflicted
// serializations:
// (1) NO per-step lgkmcnt(0) fence: the DS pipe is in-order per wave, so a
//     later ds_read is guaranteed to observe an earlier same-wave ds_write;
//     only the read DATA needs a wait and the compiler emits a precise
//     lgkmcnt(N) for that. The full drain exposed ~100-200 cyc of write
//     latency every step.
// (2) Input row preloaded to LDS: the per-step uniform load was SMEM, which
//     shares lgkmcnt with DS and entangled/over-drained the DS queue. Now
//     it's one broadcast ds_read_b32 in the same in-order DS stream.
__global__
__attribute__((amdgpu_flat_work_group_size(64, 64), amdgpu_waves_per_eu(1, 1)))
void horn_kernel(
    const float* __restrict__ input,   // (1024, 784)
    const float* __restrict__ w_ih,    // (94, 1)
    const float* __restrict__ b_ih,    // (94)
    const float* __restrict__ w_hh,    // (94, 94)
    const float* __restrict__ b_hh,    // (94)
    const float* __restrict__ w_ro,    // (10, 94)
    const float* __restrict__ b_ro,    // (10)
    float* __restrict__ out)           // (1024, 10)
{
    __shared__ __align__(16) _Float16 ysh[96];     // y exchange (f16)
    __shared__ __align__(16) float    sin_l[SEQ_LEN]; // input row (f32)
    __shared__ __align__(16) float    xsh[96];     // epilogue x gather

    const int lane = threadIdx.x;      // 0..63
    const int g    = lane >> 3;        // row-group: rows 12g..12g+11
    const int lw   = lane & 7;         // col-chunk: cols 12lw..12lw+11
    const int bb   = blockIdx.x;       // batch element

    const int b0  = lane & 1, b1 = (lane >> 1) & 1, b2v = (lane >> 2) & 1;
    const int c0i = b0 ^ b2v;
    const int c1i = b1 ^ b2v;
    const int c2i = b2v;

    const int row0 = 12 * g, col0 = 12 * lw;

    // ---- preload input row to LDS (784 floats, float4-coalesced) ----
    {
        const f4* in4 = (const f4*)(input + (size_t)bb * SEQ_LEN);
        f4* s4 = (f4*)sin_l;
        #pragma unroll 1
        for (int i = lane; i < SEQ_LEN / 4; i += 64) s4[i] = in4[i];
    }

    // ---- W block with folded row permutation (select-free butterfly),
    //      f16-packed, pre-scaled ----
    h2 w2[12][6];
    #pragma unroll
    for (int j = 0; j < 12; j++) {
        int rr;
        if (j < 8) {
            rr = row0 + 4 * (((j >> 2) & 1) ^ c2i)
                      + 2 * (((j >> 1) & 1) ^ c1i)
                      +     ((j & 1) ^ c0i);
        } else {
            const int jj = j - 8;
            rr = row0 + 8 + 2 * (((jj >> 1) & 1) ^ c1i)
                          +     ((jj & 1) ^ c0i);
        }
        #pragma unroll
        for (int c = 0; c < 12; c++) {
            const int cc = col0 + c;
            float v = (rr < NUM_NODES && cc < NUM_NODES)
                        ? w_hh[rr * NUM_NODES + cc] * WSCALE : 0.0f;
            w2[j][c >> 1][c & 1] = (_Float16)v;
        }
    }

    // Owned rows (verified machinery R6-R11):
    const int nA = row0 + 4 * c2i + 2 * c1i + c0i;
    const int nB = row0 + 8 + 2 * c1i + c0i;
    const float wihA  = (nA < NUM_NODES) ? w_ih[nA] * WSCALE : 0.0f;
    const float biasA = (nA < NUM_NODES) ? (b_ih[nA] + b_hh[nA]) * WSCALE : 0.0f;
    const float wihB  = (nB < NUM_NODES) ? w_ih[nB] * WSCALE : 0.0f;
    const float biasB = (nB < NUM_NODES) ? (b_ih[nB] + b_hh[nB]) * WSCALE : 0.0f;

    float xA = 0.0f, yA = 0.0f, xB = 0.0f, yB = 0.0f;

    // Init published y (nA unique over 64 lanes, nB pair-duplicated).
    ysh[nA] = (_Float16)0.0f;
    ysh[nB] = (_Float16)0.0f;
    // One-time ordering point: init writes + input preload before the loop.
    asm volatile("s_waitcnt lgkmcnt(0) vmcnt(0)" ::: "memory");

    const h4* yv4 = (const h4*)&ysh[col0];     // byte 24*lw: 8B-aligned

    for (int t = 0; t < SEQ_LEN; t++) {
        // ---- read own 12-col y chunk + input scalar (in-order DS stream;
        //      compiler inserts the minimal lgkmcnt for the data) ----
        h4 Y0 = yv4[0], Y1 = yv4[1], Y2 = yv4[2];
        float st = sin_l[t];                   // broadcast ds_read_b32
        h2 yy0 = __builtin_shufflevector(Y0, Y0, 0, 1);
        h2 yy1 = __builtin_shufflevector(Y0, Y0, 2, 3);
        h2 yy2 = __builtin_shufflevector(Y1, Y1, 0, 1);
        h2 yy3 = __builtin_shufflevector(Y1, Y1, 2, 3);
        h2 yy4 = __builtin_shufflevector(Y2, Y2, 0, 1);
        h2 yy5 = __builtin_shufflevector(Y2, Y2, 2, 3);

        // ---- 12 rows x 12 cols: 72 v_dot2_f32_f16 (f32 accumulate) ----
        float P[12];
        #pragma unroll
        for (int i = 0; i < 12; i++) {
            float p = dot2(w2[i][0], yy0, 0.0f);
            p = dot2(w2[i][1], yy1, p);
            p = dot2(w2[i][2], yy2, p);
            p = dot2(w2[i][3], yy3, p);
            p = dot2(w2[i][4], yy4, p);
            p = dot2(w2[i][5], yy5, p);
            P[i] = p;
        }

        // ---- select-free butterfly (row permutation folded at load) ----
        float Q0 = P[0]  + dpp_xor1(P[1]);
        float Q1 = P[2]  + dpp_xor1(P[3]);
        float Q2 = P[4]  + dpp_xor1(P[5]);
        float Q3 = P[6]  + dpp_xor1(P[7]);
        float Q4 = P[8]  + dpp_xor1(P[9]);
        float Q5 = P[10] + dpp_xor1(P[11]);
        float R0 = Q0 + dpp_xor2(Q1);
        float R1 = Q2 + dpp_xor2(Q3);
        float R2 = Q4 + dpp_xor2(Q5);
        float SA = R0 + dpp_mir8(R1);          // full dot, row nA
        float SB = R2 + dpp_mir8(R2);          // full dot, row nB

        // ---- dynamics (f32 state) ----
        float eA = __builtin_amdgcn_exp2f(fmaf(st, wihA, biasA) + SA);
        float aA = 0.5f - __builtin_amdgcn_rcpf(eA + 1.0f);  // 0.5*tanh(A)
        aA = fmaf(-TWO_GAMMA, yA, aA);
        aA = fmaf(-OM2, xA, aA);
        xA += yA;  yA += aA;

        float eB = __builtin_amdgcn_exp2f(fmaf(st, wihB, biasB) + SB);
        float aB = 0.5f - __builtin_amdgcn_rcpf(eB + 1.0f);
        aB = fmaf(-TWO_GAMMA, yB, aB);
        aB = fmaf(-OM2, xB, aB);
        xB += yB;  yB += aB;

        // ---- publish new y (NO fence: DS pipe is in-order per wave, the
        //      next iteration's ds_read is ordered after these writes) ----
        ysh[nA] = (_Float16)yA;
        ysh[nB] = (_Float16)yB;      // pair-duplicate same value: benign
    }

    // ---- epilogue: gather x (f32), project to classes ----
    xsh[nA] = xA;
    xsh[nB] = xB;
    asm volatile("s_waitcnt lgkmcnt(0)" ::: "memory");

    if (lane < OUT_CLASSES) {
        float acc = b_ro[lane];
        #pragma unroll 2
        for (int j = 0; j < NUM_NODES; j++) {
            acc += xsh[j] * w_ro[lane * NUM_NODES + j];
        }
        out[(size_t)bb * OUT_CLASSES + lane] = acc;
    }
}

extern "C" void kernel_launch(void* const* d_in, const int* in_sizes, int n_in,
                              void* d_out, int out_size, void* d_ws, size_t ws_size,
                              hipStream_t stream) {
    const float* input = (const float*)d_in[0];
    const float* w_ih  = (const float*)d_in[1];
    const float* b_ih  = (const float*)d_in[2];
    const float* w_hh  = (const float*)d_in[3];
    const float* b_hh  = (const float*)d_in[4];
    const float* w_ro  = (const float*)d_in[5];
    const float* b_ro  = (const float*)d_in[6];
    float* out = (float*)d_out;

    const int batch = in_sizes[0] / SEQ_LEN;   // 1024
    dim3 grid(batch);                          // 1 element per 1-wave block
    dim3 block(64);

    hipLaunchKernelGGL(horn_kernel, grid, block, 0, stream,
                       input, w_ih, b_ih, w_hh, b_hh, w_ro, b_ro, out);
}

// Round 14
// 308.561 us; speedup vs baseline: 1.5925x; 1.0003x over previous
//
#include <hip/hip_runtime.h>
#include <math.h>

#define NUM_NODES 94
#define SEQ_LEN 784
#define OUT_CLASSES 10

#define TWO_GAMMA 0.2f
#define OM2 0.0503551324598949f            // (2*pi/28)^2
#define INV_SQRT_N 0.103142124625879       // 1/sqrt(94)
#define LOG2E 1.4426950408889634
// exp2 arg = 2A*log2e -> fold 2*INV_SQRT_N*LOG2E into all I-path weights
#define WSCALE ((float)(2.0 * INV_SQRT_N * LOG2E))

typedef _Float16 h2 __attribute__((ext_vector_type(2)));
typedef _Float16 h4 __attribute__((ext_vector_type(4)));
typedef float f4 __attribute__((ext_vector_type(4)));

__device__ __forceinline__ float dpp_xor1(float x) {   // quad_perm(1,0,3,2)
    return __int_as_float(__builtin_amdgcn_mov_dpp(__float_as_int(x), 0xB1, 0xF, 0xF, true));
}
__device__ __forceinline__ float dpp_xor2(float x) {   // quad_perm(2,3,0,1)
    return __int_as_float(__builtin_amdgcn_mov_dpp(__float_as_int(x), 0x4E, 0xF, 0xF, true));
}
__device__ __forceinline__ float dpp_mir8(float x) {   // ROW_HALF_MIRROR: i<->i^7
    return __int_as_float(__builtin_amdgcn_mov_dpp(__float_as_int(x), 0x141, 0xF, 0xF, true));
}

__device__ __forceinline__ float dot2(h2 a, h2 b, float c) {
#if __has_builtin(__builtin_amdgcn_fdot2)
    return __builtin_amdgcn_fdot2(a, b, c, false);   // v_dot2_f32_f16
#else
    return c + (float)a[0] * (float)b[0] + (float)a[1] * (float)b[1];
#endif
}

// R13 skeleton (best=265us, absmax 1.95e-3). R14 micro-opts:
// (1) input scalar prefetched one step ahead -- in R13 its ds_read queued
//     BEHIND the y-writes in the in-order DS pipe every step; now it's read
//     during the previous step and enters the dynamics from a register.
// (2) waves_per_eu(1,4): min=1 keeps the 512-VGPR budget; max=4 lets an
//     imbalanced 5th block on a CU co-schedule instead of serializing.
// (3) t-loop unrolled x2: halves loop overhead, wider scheduling window.
__global__
__attribute__((amdgpu_flat_work_group_size(64, 64), amdgpu_waves_per_eu(1, 4)))
void horn_kernel(
    const float* __restrict__ input,   // (1024, 784)
    const float* __restrict__ w_ih,    // (94, 1)
    const float* __restrict__ b_ih,    // (94)
    const float* __restrict__ w_hh,    // (94, 94)
    const float* __restrict__ b_hh,    // (94)
    const float* __restrict__ w_ro,    // (10, 94)
    const float* __restrict__ b_ro,    // (10)
    float* __restrict__ out)           // (1024, 10)
{
    __shared__ __align__(16) _Float16 ysh[96];        // y exchange (f16)
    __shared__ __align__(16) float    sin_l[SEQ_LEN]; // input row (f32)
    __shared__ __align__(16) float    xsh[96];        // epilogue x gather

    const int lane = threadIdx.x;      // 0..63
    const int g    = lane >> 3;        // row-group: rows 12g..12g+11
    const int lw   = lane & 7;         // col-chunk: cols 12lw..12lw+11
    const int bb   = blockIdx.x;       // batch element

    const int b0  = lane & 1, b1 = (lane >> 1) & 1, b2v = (lane >> 2) & 1;
    const int c0i = b0 ^ b2v;
    const int c1i = b1 ^ b2v;
    const int c2i = b2v;

    const int row0 = 12 * g, col0 = 12 * lw;

    // ---- preload input row to LDS (784 floats, float4-coalesced) ----
    {
        const f4* in4 = (const f4*)(input + (size_t)bb * SEQ_LEN);
        f4* s4 = (f4*)sin_l;
        #pragma unroll 1
        for (int i = lane; i < SEQ_LEN / 4; i += 64) s4[i] = in4[i];
    }

    // ---- W block with folded row permutation (select-free butterfly),
    //      f16-packed, pre-scaled ----
    h2 w2[12][6];
    #pragma unroll
    for (int j = 0; j < 12; j++) {
        int rr;
        if (j < 8) {
            rr = row0 + 4 * (((j >> 2) & 1) ^ c2i)
                      + 2 * (((j >> 1) & 1) ^ c1i)
                      +     ((j & 1) ^ c0i);
        } else {
            const int jj = j - 8;
            rr = row0 + 8 + 2 * (((jj >> 1) & 1) ^ c1i)
                          +     ((jj & 1) ^ c0i);
        }
        #pragma unroll
        for (int c = 0; c < 12; c++) {
            const int cc = col0 + c;
            float v = (rr < NUM_NODES && cc < NUM_NODES)
                        ? w_hh[rr * NUM_NODES + cc] * WSCALE : 0.0f;
            w2[j][c >> 1][c & 1] = (_Float16)v;
        }
    }

    // Owned rows (verified machinery R6-R13):
    const int nA = row0 + 4 * c2i + 2 * c1i + c0i;
    const int nB = row0 + 8 + 2 * c1i + c0i;
    const float wihA  = (nA < NUM_NODES) ? w_ih[nA] * WSCALE : 0.0f;
    const float biasA = (nA < NUM_NODES) ? (b_ih[nA] + b_hh[nA]) * WSCALE : 0.0f;
    const float wihB  = (nB < NUM_NODES) ? w_ih[nB] * WSCALE : 0.0f;
    const float biasB = (nB < NUM_NODES) ? (b_ih[nB] + b_hh[nB]) * WSCALE : 0.0f;

    float xA = 0.0f, yA = 0.0f, xB = 0.0f, yB = 0.0f;

    // Init published y (nA unique over 64 lanes, nB pair-duplicated).
    ysh[nA] = (_Float16)0.0f;
    ysh[nB] = (_Float16)0.0f;
    // One-time ordering point: init writes + input preload before the loop.
    asm volatile("s_waitcnt lgkmcnt(0) vmcnt(0)" ::: "memory");

    const h4* yv4 = (const h4*)&ysh[col0];     // byte 24*lw: 8B-aligned

    float st = sin_l[0];                       // step-0 input (prefetched)

    #pragma unroll 2
    for (int t = 0; t < SEQ_LEN; t++) {
        // ---- read own 12-col y chunk; prefetch NEXT step's input scalar
        //      (goes into the DS queue ahead of this step's y-writes) ----
        h4 Y0 = yv4[0], Y1 = yv4[1], Y2 = yv4[2];
        const int tn = (t + 1 < SEQ_LEN) ? t + 1 : (SEQ_LEN - 1);
        float stn = sin_l[tn];
        h2 yy0 = __builtin_shufflevector(Y0, Y0, 0, 1);
        h2 yy1 = __builtin_shufflevector(Y0, Y0, 2, 3);
        h2 yy2 = __builtin_shufflevector(Y1, Y1, 0, 1);
        h2 yy3 = __builtin_shufflevector(Y1, Y1, 2, 3);
        h2 yy4 = __builtin_shufflevector(Y2, Y2, 0, 1);
        h2 yy5 = __builtin_shufflevector(Y2, Y2, 2, 3);

        // ---- 12 rows x 12 cols: 72 v_dot2_f32_f16 (f32 accumulate) ----
        float P[12];
        #pragma unroll
        for (int i = 0; i < 12; i++) {
            float p = dot2(w2[i][0], yy0, 0.0f);
            p = dot2(w2[i][1], yy1, p);
            p = dot2(w2[i][2], yy2, p);
            p = dot2(w2[i][3], yy3, p);
            p = dot2(w2[i][4], yy4, p);
            p = dot2(w2[i][5], yy5, p);
            P[i] = p;
        }

        // ---- select-free butterfly (row permutation folded at load) ----
        float Q0 = P[0]  + dpp_xor1(P[1]);
        float Q1 = P[2]  + dpp_xor1(P[3]);
        float Q2 = P[4]  + dpp_xor1(P[5]);
        float Q3 = P[6]  + dpp_xor1(P[7]);
        float Q4 = P[8]  + dpp_xor1(P[9]);
        float Q5 = P[10] + dpp_xor1(P[11]);
        float R0 = Q0 + dpp_xor2(Q1);
        float R1 = Q2 + dpp_xor2(Q3);
        float R2 = Q4 + dpp_xor2(Q5);
        float SA = R0 + dpp_mir8(R1);          // full dot, row nA
        float SB = R2 + dpp_mir8(R2);          // full dot, row nB

        // ---- dynamics (f32 state; st already in a register) ----
        float eA = __builtin_amdgcn_exp2f(fmaf(st, wihA, biasA) + SA);
        float aA = 0.5f - __builtin_amdgcn_rcpf(eA + 1.0f);  // 0.5*tanh(A)
        aA = fmaf(-TWO_GAMMA, yA, aA);
        aA = fmaf(-OM2, xA, aA);
        xA += yA;  yA += aA;
        ysh[nA] = (_Float16)yA;                // publish ASAP

        float eB = __builtin_amdgcn_exp2f(fmaf(st, wihB, biasB) + SB);
        float aB = 0.5f - __builtin_amdgcn_rcpf(eB + 1.0f);
        aB = fmaf(-TWO_GAMMA, yB, aB);
        aB = fmaf(-OM2, xB, aB);
        xB += yB;  yB += aB;
        ysh[nB] = (_Float16)yB;                // pair-duplicate: benign
        // NO fence: DS pipe is in-order per wave; next iteration's ds_read
        // is ordered after these writes, and its data-wait is compiler-emitted.

        st = stn;
    }

    // ---- epilogue: gather x (f32), project to classes ----
    xsh[nA] = xA;
    xsh[nB] = xB;
    asm volatile("s_waitcnt lgkmcnt(0)" ::: "memory");

    if (lane < OUT_CLASSES) {
        float acc = b_ro[lane];
        #pragma unroll 2
        for (int j = 0; j < NUM_NODES; j++) {
            acc += xsh[j] * w_ro[lane * NUM_NODES + j];
        }
        out[(size_t)bb * OUT_CLASSES + lane] = acc;
    }
}

extern "C" void kernel_launch(void* const* d_in, const int* in_sizes, int n_in,
                              void* d_out, int out_size, void* d_ws, size_t ws_size,
                              hipStream_t stream) {
    const float* input = (const float*)d_in[0];
    const float* w_ih  = (const float*)d_in[1];
    const float* b_ih  = (const float*)d_in[2];
    const float* w_hh  = (const float*)d_in[3];
    const float* b_hh  = (const float*)d_in[4];
    const float* w_ro  = (const float*)d_in[5];
    const float* b_ro  = (const float*)d_in[6];
    float* out = (float*)d_out;

    const int batch = in_sizes[0] / SEQ_LEN;   // 1024
    dim3 grid(batch);                          // 1 element per 1-wave block
    dim3 block(64);

    hipLaunchKernelGGL(horn_kernel, grid, block, 0, stream,
                       input, w_ih, b_ih, w_hh, b_hh, w_ro, b_ro, out);
}